// Round 10
// baseline (125.531 us; speedup 1.0000x reference)
//
#include <hip/hip_runtime.h>
#include <math.h>

#define BB 8
#define HH 256
#define KK 256
#define EE 128
#define NBIN 1024            // 1000 value-vocab bins padded to 1024
#define HJ 8                 // h rows per K1 block
#define BPB (HH / HJ)        // 32 K1 blocks per b
#define NB1 (BB * BPB)       // 256 K1 blocks

// DPP-based add: x + dpp_mov(x).
template <int CTRL, int RM>
__device__ __forceinline__ float dpp_add(float x) {
    int d = __builtin_amdgcn_update_dpp(0, __float_as_int(x), CTRL, RM, 0xf, true);
    return x + __int_as_float(d);
}
// Sum within each 32-lane half; lanes 31/63 hold the result.
__device__ __forceinline__ float dpp_reduce_half(float x) {
    x = dpp_add<0x111, 0xf>(x);  // row_shr:1
    x = dpp_add<0x112, 0xf>(x);  // row_shr:2
    x = dpp_add<0x114, 0xf>(x);  // row_shr:4
    x = dpp_add<0x118, 0xf>(x);  // row_shr:8
    x = dpp_add<0x142, 0xa>(x);  // row_bcast:15 -> lanes 31,63 have 32-sums
    return x;
}
// Sum over all 64 lanes; lane 63 holds the result.
__device__ __forceinline__ float dpp_reduce_wave(float x) {
    x = dpp_reduce_half(x);
    x = dpp_add<0x143, 0xc>(x);  // row_bcast:31 -> lane 63 has 64-sum
    return x;
}

// ---------------- K1: 256 blocks x (b, 8-h tile). Attention -> LDS hist. ----------------
// Each key row is loaded ONCE per block and dotted against 8 hidden rows:
// key-gather traffic = 256 x 128 KB = 33.5 MB (vs 268 MB at 1 h/block).
__global__ __launch_bounds__(256) void kvmn_attn(
    const float* __restrict__ hidden,     // [B,H,E]
    const float* __restrict__ key_emb,    // [VOCAB,E]
    const int*   __restrict__ key_seq,    // [B,K]
    const int*   __restrict__ value_seq,  // [B,H,K]
    const int*   __restrict__ mask,       // [B,H,K]
    float* __restrict__ part_hist,        // [NB1, NBIN]  (1 MB)
    int*   __restrict__ c_part,           // [NB1]
    float* __restrict__ sum_ws,           // [B,E]  zeroed by block 0
    int*   __restrict__ ticket)           // [B]    zeroed by block 0
{
    __shared__ float sh_u[HJ][KK];
    __shared__ float hist[NBIN];
    __shared__ float fslot[HJ][4];
    __shared__ int   islot[HJ][4];

    const int bid  = blockIdx.x;
    const int b    = bid >> 5;            // / BPB
    const int h0   = (bid & 31) * HJ;
    const int tid  = threadIdx.x;         // == k
    const int w    = tid >> 6;
    const int lane = tid & 63;
    const int half = lane >> 5;
    const int sub  = lane & 31;

    // block 0 zeroes the K2 accumulators (visible at K2 launch: kernel boundary)
    if (bid == 0) {
        if (tid < BB * EE / 4)
            *(float4*)&sum_ws[tid * 4] = make_float4(0.f, 0.f, 0.f, 0.f);
        if (tid < BB) ticket[tid] = 0;
    }

    const int ksreg = key_seq[b * KK + tid];

    float4 h4[HJ];
    #pragma unroll
    for (int j = 0; j < HJ; ++j)
        h4[j] = *(const float4*)&hidden[((size_t)b * HH + h0 + j) * EE + sub * 4];

    *(float4*)&hist[tid * 4] = make_float4(0.f, 0.f, 0.f, 0.f);

    const float inv_scale = 0.08838834764831845f; // 1/sqrt(128)

    // phase 1: each half-wave loads one key row per iter; 8 dots + 8 DPP chains
    #pragma unroll 4
    for (int i = 0; i < 32; ++i) {
        const int    row = __shfl(ksreg, half * 32 + i, 64);
        const float4 kv  = *(const float4*)&key_emb[(size_t)row * EE + sub * 4];
        const int    k2  = w * 64 + half * 32 + i;
        #pragma unroll
        for (int j = 0; j < HJ; ++j) {
            float part = kv.x * h4[j].x + kv.y * h4[j].y + kv.z * h4[j].z + kv.w * h4[j].w;
            part = dpp_reduce_half(part);          // independent chains: pipelined
            if (sub == 31) sh_u[j][k2] = part * inv_scale;
        }
    }
    __syncthreads();

    // phase 2: per h row: d = exp(u)*mask; block denom; validity flag
    float d[HJ];
    int   vs[HJ];
    #pragma unroll
    for (int j = 0; j < HJ; ++j) {
        const size_t idx = ((size_t)b * HH + h0 + j) * KK + tid;
        const int m = mask[idx];
        vs[j] = value_seq[idx];
        d[j]  = expf(sh_u[j][tid]) * (float)m;
        const float s = dpp_reduce_wave(d[j]);
        if (lane == 63) fslot[j][w] = s;
        const unsigned long long bal = __ballot(m != 0 && vs[j] != 0);
        if (lane == 0) islot[j][w] = (bal != 0ull) ? 1 : 0;
    }
    __syncthreads();

    // p scatter into the block-shared histogram (8 h rows accumulate together)
    #pragma unroll
    for (int j = 0; j < HJ; ++j) {
        const float denom = fslot[j][0] + fslot[j][1] + fslot[j][2] + fslot[j][3];
        const float p = d[j] * (1.0f / (denom + 1e-10f));
        atomicAdd(&hist[vs[j]], p);
    }
    if (tid == 0) {
        int c = 0;
        #pragma unroll
        for (int j = 0; j < HJ; ++j)
            c += (islot[j][0] | islot[j][1] | islot[j][2] | islot[j][3]);
        c_part[bid] = c;
    }
    __syncthreads();

    *(float4*)&part_hist[(size_t)bid * NBIN + tid * 4] = *(float4*)&hist[tid * 4];
}

// ---------------- K2: 64 blocks = (b, 128-bin chunk). Hist reduce + GEMM + last-block finalize. ----------------
__global__ __launch_bounds__(256) void kvmn_hgemm(
    const float* __restrict__ part_hist,  // [NB1, NBIN]
    const int*   __restrict__ c_part,     // [NB1]
    const float* __restrict__ value_emb,  // [FVOCAB, E]
    float* __restrict__ sum_ws,           // [B, E]
    int*   __restrict__ ticket,           // [B]
    float* __restrict__ out)              // [B, E]
{
    __shared__ float Hsh[2][128];
    __shared__ float gs[2][EE];
    __shared__ bool  isLast;
    __shared__ float sh_cf;

    const int bid = blockIdx.x;           // 64
    const int b   = bid >> 3;
    const int ch  = bid & 7;              // bins [ch*128, ch*128+128)
    const int tid = threadIdx.x;
    const int bin = tid & 127;
    const int rh  = tid >> 7;

    // reduce this b's 32 hist rows over the 128-bin slice
    float s = 0.0f;
    const float* base = part_hist + ((size_t)(b * BPB) + rh * 16) * NBIN + ch * 128 + bin;
    #pragma unroll 8
    for (int r = 0; r < 16; ++r)
        s += base[(size_t)r * NBIN];
    Hsh[rh][bin] = s;
    __syncthreads();
    if (tid < 128) Hsh[0][tid] += Hsh[1][tid];
    __syncthreads();

    // chunk GEMM: pout[e] = sum_{i in chunk} H[i] * V[ch*128+i, e]
    const int e  = tid & 127;
    const int hf = tid >> 7;
    float acc = 0.0f;
    #pragma unroll 8
    for (int i = 0; i < 64; ++i) {
        const int gb = ch * 128 + hf * 64 + i;
        if (gb < 1000)
            acc += Hsh[0][hf * 64 + i] * value_emb[(size_t)gb * EE + e];
    }
    gs[hf][e] = acc;
    __syncthreads();

    if (tid < 128) atomicAdd(&sum_ws[b * EE + tid], gs[0][tid] + gs[1][tid]);
    __threadfence();                       // make this block's adds visible
    __syncthreads();
    if (tid == 0) {
        const int old = atomicAdd(&ticket[b], 1);
        isLast = (old == 7);               // 8 chunk-blocks per b
    }
    __syncthreads();

    if (isLast) {
        __threadfence();                   // see all other blocks' adds
        if (tid == 0) {
            int c = 0;
            #pragma unroll
            for (int r = 0; r < BPB; ++r) c += c_part[b * BPB + r];
            sh_cf = (float)c;
        }
        __syncthreads();
        if (tid < EE)
            out[b * EE + tid] = sum_ws[b * EE + tid] / sh_cf;
    }
}

extern "C" void kernel_launch(void* const* d_in, const int* in_sizes, int n_in,
                              void* d_out, int out_size, void* d_ws, size_t ws_size,
                              hipStream_t stream) {
    const float* hidden    = (const float*)d_in[0];
    const float* key_emb   = (const float*)d_in[1];
    const float* value_emb = (const float*)d_in[2];
    const int*   key_seq   = (const int*)d_in[3];
    const int*   value_seq = (const int*)d_in[4];
    const int*   mask      = (const int*)d_in[5];

    char* ws = (char*)d_ws;
    float* part_hist = (float*)ws;                               // 1 MB
    int*   c_part    = (int*)  (ws + (1u << 20));                // 1 KB
    float* sum_ws    = (float*)(ws + (1u << 20) + 1024);         // 4 KB
    int*   ticket    = (int*)  (ws + (1u << 20) + 1024 + 4096);  // 32 B

    kvmn_attn <<<NB1, 256, 0, stream>>>(hidden, key_emb, key_seq, value_seq, mask,
                                        part_hist, c_part, sum_ws, ticket);
    kvmn_hgemm<<<64, 256, 0, stream>>>(part_hist, c_part, value_emb,
                                       sum_ws, ticket, (float*)d_out);
    (void)in_sizes; (void)n_in; (void)out_size; (void)ws_size;
}